// Round 2
// baseline (205.805 us; speedup 1.0000x reference)
//
#include <hip/hip_runtime.h>
#include <hip/hip_bf16.h>

// ModulatedConv2d: out = oscale[b,co] * conv2d(s[b,ci]*x, w_bf16)
// B=8, C=512, K=3, H=W=64.
// Round 2: 128co x 8row x 64col blocks (256 blocks = 1/CU), m=8 reuse,
// lane-linear A-frag layout (conflict-free), 8-distinct x swizzle.

#define CDIM 512
#define HW 64
#define CK 32
#define NCHUNK 16   // 512/32

typedef __attribute__((ext_vector_type(8))) short short8;
typedef __attribute__((ext_vector_type(4))) float float4v;

__device__ __forceinline__ short f2bf(float f) {
    unsigned u = __float_as_uint(f);
    unsigned r = (u + 0x7FFFu + ((u >> 16) & 1u)) >> 16;
    return (short)r;
}

__device__ __forceinline__ void async_ld16(const short* g, short* l) {
    __builtin_amdgcn_global_load_lds(
        (const __attribute__((address_space(1))) void*)g,
        (__attribute__((address_space(3))) void*)l, 16, 0, 0);
}

// ---------------- prep kernels ----------------

__global__ void k_affine(const float* __restrict__ style, const float* __restrict__ aw,
                         const float* __restrict__ ab, float* __restrict__ s) {
    int b = blockIdx.x;
    int ci = blockIdx.y * 256 + threadIdx.x;
    const float* st = style + b * CDIM;
    const float* w = aw + ci * CDIM;
    float acc = 0.f;
    for (int k = 0; k < CDIM; ++k) acc += st[k] * w[k];
    s[b * CDIM + ci] = acc * 0.04419417382415922f + ab[ci];
}

__global__ void k_ws2(const float* __restrict__ w, float* __restrict__ ws2) {
    int i = blockIdx.x * 256 + threadIdx.x;  // 262144
    const float* p = w + i * 9;
    float a = 0.f;
#pragma unroll
    for (int t = 0; t < 9; ++t) a += p[t] * p[t];
    ws2[i] = a;
}

__global__ void k_oscale(const float* __restrict__ s, const float* __restrict__ ws2,
                         float* __restrict__ osc) {
    __shared__ float s2[CDIM];
    int b = blockIdx.x;
    int co = blockIdx.y * 256 + threadIdx.x;
    for (int i = threadIdx.x; i < CDIM; i += 256) {
        float v = s[b * CDIM + i];
        s2[i] = v * v;
    }
    __syncthreads();
    const float* r = ws2 + co * CDIM;
    float acc = 0.f;
    for (int k = 0; k < CDIM; ++k) acc += s2[k] * r[k];
    const float wg = 0.014731391274719739f;          // 1/sqrt(4608)
    const float wg2 = 2.170138888888889e-4f;         // 1/4608
    osc[b * CDIM + co] = wg * rsqrtf(wg2 * acc + 1e-8f);
}

// wgt layout: [chunk16][ct4] regions of 36864 shorts.
// Within region: [t9][mf8][slot64][j8], slot = l4*16 + l15 (lane-linear),
// value = w[co = ct*128 + mf*16 + l15][ci = chunk*32 + l4*8 + j][t]
__global__ void k_wconv(const float* __restrict__ w, short* __restrict__ wgt) {
    int idx = blockIdx.x * 256 + threadIdx.x;  // 2359296
    int j = idx & 7;
    int slotg = idx >> 3;              // global 16B-slot index, 0..294911
    int region = slotg / 4608;         // chunk*4 + ct
    int a16 = slotg - region * 4608;   // 0..4607
    int tm = a16 >> 6;                 // t*8 + mf
    int t = tm >> 3;
    int mf = tm & 7;
    int sl = a16 & 63;
    int l4 = sl >> 4;
    int l15 = sl & 15;
    int ct = region & 3;
    int c = region >> 2;
    int co = ct * 128 + mf * 16 + l15;
    int ci = c * 32 + l4 * 8 + j;
    wgt[idx] = f2bf(w[(co * CDIM + ci) * 9 + t]);
}

// ---------------- main conv ----------------
// grid 256 blocks x 512 threads. Block: (ct co-tile of 128, b, row-tile of 8).
__global__ __launch_bounds__(512, 2) void conv_main(
    const float* __restrict__ x, const float* __restrict__ s,
    const short* __restrict__ wgt, const float* __restrict__ osc,
    float* __restrict__ out) {

    __shared__ __align__(16) short w_lds[9 * 8 * 64 * 8];    // 36864 sh = 73728 B
    __shared__ __align__(16) short x_lds[2][10 * 66 * CK];   // 2*42240 B

    const int tid = threadIdx.x;
    const int lane = tid & 63;
    const int wid = tid >> 6;          // 0..7 = output row within tile
    const int l15 = lane & 15;
    const int l4 = lane >> 4;

    // XCD-aware mapping: xcd = bx%8 = ct*2 + (b&1); blocks on one XCD share
    // the W stream (same ct) and half the x slices (same b parity).
    const int bx = blockIdx.x;
    const int ct = (bx >> 1) & 3;
    const int bpar = bx & 1;
    const int rest = bx >> 3;          // 0..31
    const int b = 2 * (rest & 3) + bpar;
    const int rt = rest >> 2;          // 0..7
    const int r0 = rt * 8;

    // staging lane mapping: 4 cig x 64 col x 2 rowhalf
    const int cig = tid & 3;               // ci 8-block
    const int col = (tid >> 2) & 63;
    const int rowhalf = tid >> 8;          // 0/1

    // zero halo columns (lcol 0 and 65) of both buffers, once (uint writes)
    for (int i = tid; i < 640; i += 512) {
        int bufi = i >= 320;
        int v = i - bufi * 320;
        int row = v >> 5;
        int w16 = v & 31;
        int colh = (w16 >= 16) ? 65 : 0;
        int q16 = w16 & 15;
        ((unsigned*)x_lds[bufi])[(row * 66 + colh) * 16 + q16] = 0u;
    }

    float rx[40];
    float4v sva, svb;

    auto stage_w = [&](int c) {
        const short* src = wgt + (c * 4 + ct) * 36864;
#pragma unroll
        for (int k = 0; k < 9; ++k) {
            int off = (k * 512 + wid * 64) * 8;   // shorts, wave-uniform
            async_ld16(src + off + lane * 8, w_lds + off);
        }
    };

    auto stage_x_load = [&](int c) {
        const float4v* sp = (const float4v*)&s[b * CDIM + c * 32 + cig * 8];
        sva = sp[0]; svb = sp[1];
#pragma unroll
        for (int i = 0; i < 5; ++i) {
            int row = 2 * i + rowhalf;         // 0..9
            int grow = r0 - 1 + row;
            bool ok = (grow >= 0) && (grow < HW);
            const float* base = x + ((b * CDIM + c * 32 + cig * 8) * HW + (ok ? grow : 0)) * HW + col;
#pragma unroll
            for (int j = 0; j < 8; ++j) {
                float v = base[j * (HW * HW)];
                rx[i * 8 + j] = ok ? v : 0.0f;
            }
        }
    };

    auto stage_x_write = [&](int buf) {
        int lcol = col + 1;
        int q = cig ^ ((lcol >> 1) & 3);
#pragma unroll
        for (int i = 0; i < 5; ++i) {
            int row = 2 * i + rowhalf;
            short8 pk;
#pragma unroll
            for (int j = 0; j < 8; ++j) {
                float sj = (j < 4) ? sva[j] : svb[j - 4];
                pk[j] = f2bf(rx[i * 8 + j] * sj);
            }
            *(short8*)&x_lds[buf][(row * 66 + lcol) * CK + q * 8] = pk;
        }
    };

    float4v acc[8][4] = {};

    auto compute = [&](int buf) {
        const short* xb = x_lds[buf];
#pragma unroll
        for (int t = 0; t < 9; ++t) {
            int dh = t / 3 - 1;
            int dw = t % 3 - 1;
            int lrow = wid + dh + 1;   // 0..9
            short8 bfr[4];
#pragma unroll
            for (int nf = 0; nf < 4; ++nf) {
                int lcol = 1 + nf * 16 + l15 + dw;
                int xq = l4 ^ ((lcol >> 1) & 3);
                bfr[nf] = *(const short8*)&xb[(lrow * 66 + lcol) * CK + xq * 8];
            }
#pragma unroll
            for (int mf = 0; mf < 8; ++mf) {
                short8 af = *(const short8*)&w_lds[((t * 8 + mf) * 64 + lane) * 8];
#pragma unroll
                for (int nf = 0; nf < 4; ++nf)
                    acc[mf][nf] = __builtin_amdgcn_mfma_f32_16x16x32_bf16(
                        af, bfr[nf], acc[mf][nf], 0, 0, 0);
            }
        }
    };

    // prologue
    stage_w(0);
    stage_x_load(0);
    stage_x_write(0);
    __syncthreads();

    int cur = 0;
#pragma unroll 1
    for (int c = 0; c < NCHUNK; ++c) {
        if (c + 1 < NCHUNK) stage_x_load(c + 1);   // issue early, hide under MFMA
        compute(cur);
        if (c + 1 < NCHUNK) {
            __syncthreads();                        // all done with w_lds & x_lds[cur^1]
            stage_w(c + 1);                         // async global->LDS
            stage_x_write(cur ^ 1);                 // modulate + bf16 + ds_write
            __syncthreads();                        // full drain (vmcnt+lgkm)
            cur ^= 1;
        }
    }

    // epilogue: demodulate + store
    const int row_out = r0 + wid;
#pragma unroll
    for (int mf = 0; mf < 8; ++mf) {
        float4v ov = *(const float4v*)&osc[b * CDIM + ct * 128 + mf * 16 + l4 * 4];
#pragma unroll
        for (int j = 0; j < 4; ++j) {
            int co = ct * 128 + mf * 16 + l4 * 4 + j;
            float* po = out + ((b * CDIM + co) * HW + row_out) * HW;
#pragma unroll
            for (int nf = 0; nf < 4; ++nf)
                po[nf * 16 + l15] = acc[mf][nf][j] * ov[j];
        }
    }
}

// ---------------- launcher ----------------

extern "C" void kernel_launch(void* const* d_in, const int* in_sizes, int n_in,
                              void* d_out, int out_size, void* d_ws, size_t ws_size,
                              hipStream_t stream) {
    const float* x     = (const float*)d_in[0];   // 8*512*64*64
    const float* style = (const float*)d_in[1];   // 8*512
    const float* w     = (const float*)d_in[2];   // 512*512*9
    const float* aw    = (const float*)d_in[3];   // 512*512
    const float* ab    = (const float*)d_in[4];   // 512
    float* out = (float*)d_out;

    float* s_buf = (float*)d_ws;                 // 4096
    float* ws2   = s_buf + 4096;                 // 262144
    float* osc   = ws2 + 262144;                 // 4096
    short* wgt   = (short*)(osc + 4096);         // 2359296 shorts (~4.5 MB)

    k_affine<<<dim3(8, 2), 256, 0, stream>>>(style, aw, ab, s_buf);
    k_ws2<<<1024, 256, 0, stream>>>(w, ws2);
    k_wconv<<<9216, 256, 0, stream>>>(w, wgt);
    k_oscale<<<dim3(8, 2), 256, 0, stream>>>(s_buf, ws2, osc);
    conv_main<<<256, 512, 0, stream>>>(x, s_buf, wgt, osc, out);
}

// Round 4
// 205.357 us; speedup vs baseline: 1.0022x; 1.0022x over previous
//
#include <hip/hip_runtime.h>
#include <hip/hip_bf16.h>

// ModulatedConv2d: out = oscale[b,co] * conv2d(s[b,ci]*x, w_bf16)
// B=8, C=512, K=3, H=W=64.
// Round 4: explicit vmcnt/lgkm drain + raw s_barrier (close async-LDS race),
// keep launch_bounds(512,1) (no spill) and bijective b==xcd block mapping.

#define CDIM 512
#define HW 64
#define CK 32
#define NCHUNK 16   // 512/32

typedef __attribute__((ext_vector_type(8))) short short8;
typedef __attribute__((ext_vector_type(4))) float float4v;

__device__ __forceinline__ short f2bf(float f) {
    unsigned u = __float_as_uint(f);
    unsigned r = (u + 0x7FFFu + ((u >> 16) & 1u)) >> 16;
    return (short)r;
}

__device__ __forceinline__ void async_ld16(const short* g, short* l) {
    __builtin_amdgcn_global_load_lds(
        (const __attribute__((address_space(1))) void*)g,
        (__attribute__((address_space(3))) void*)l, 16, 0, 0);
}

// Explicit full-drain barrier: do not rely on compiler's waitcnt-before-barrier.
__device__ __forceinline__ void hard_sync() {
    asm volatile("s_waitcnt vmcnt(0) lgkmcnt(0)" ::: "memory");
    __builtin_amdgcn_sched_barrier(0);
    __builtin_amdgcn_s_barrier();
    __builtin_amdgcn_sched_barrier(0);
}

// ---------------- prep kernels ----------------

__global__ void k_affine(const float* __restrict__ style, const float* __restrict__ aw,
                         const float* __restrict__ ab, float* __restrict__ s) {
    int b = blockIdx.x;
    int ci = blockIdx.y * 256 + threadIdx.x;
    const float* st = style + b * CDIM;
    const float* w = aw + ci * CDIM;
    float acc = 0.f;
    for (int k = 0; k < CDIM; ++k) acc += st[k] * w[k];
    s[b * CDIM + ci] = acc * 0.04419417382415922f + ab[ci];
}

__global__ void k_ws2(const float* __restrict__ w, float* __restrict__ ws2) {
    int i = blockIdx.x * 256 + threadIdx.x;  // 262144
    const float* p = w + i * 9;
    float a = 0.f;
#pragma unroll
    for (int t = 0; t < 9; ++t) a += p[t] * p[t];
    ws2[i] = a;
}

__global__ void k_oscale(const float* __restrict__ s, const float* __restrict__ ws2,
                         float* __restrict__ osc) {
    __shared__ float s2[CDIM];
    int b = blockIdx.x;
    int co = blockIdx.y * 256 + threadIdx.x;
    for (int i = threadIdx.x; i < CDIM; i += 256) {
        float v = s[b * CDIM + i];
        s2[i] = v * v;
    }
    __syncthreads();
    const float* r = ws2 + co * CDIM;
    float acc = 0.f;
    for (int k = 0; k < CDIM; ++k) acc += s2[k] * r[k];
    const float wg = 0.014731391274719739f;          // 1/sqrt(4608)
    const float wg2 = 2.170138888888889e-4f;         // 1/4608
    osc[b * CDIM + co] = wg * rsqrtf(wg2 * acc + 1e-8f);
}

// wgt layout: [chunk16][ct4] regions of 36864 shorts.
// Within region: [t9][mf8][slot64][j8], slot = l4*16 + l15 (lane-linear),
// value = w[co = ct*128 + mf*16 + l15][ci = chunk*32 + l4*8 + j][t]
__global__ void k_wconv(const float* __restrict__ w, short* __restrict__ wgt) {
    int idx = blockIdx.x * 256 + threadIdx.x;  // 2359296
    int j = idx & 7;
    int slotg = idx >> 3;              // global 16B-slot index, 0..294911
    int region = slotg / 4608;         // chunk*4 + ct
    int a16 = slotg - region * 4608;   // 0..4607
    int tm = a16 >> 6;                 // t*8 + mf
    int t = tm >> 3;
    int mf = tm & 7;
    int sl = a16 & 63;
    int l4 = sl >> 4;
    int l15 = sl & 15;
    int ct = region & 3;
    int c = region >> 2;
    int co = ct * 128 + mf * 16 + l15;
    int ci = c * 32 + l4 * 8 + j;
    wgt[idx] = f2bf(w[(co * CDIM + ci) * 9 + t]);
}

// ---------------- main conv ----------------
// grid 256 blocks x 512 threads. Block: (ct co-tile of 128, b, row-tile of 8).
__global__ __launch_bounds__(512, 1) void conv_main(
    const float* __restrict__ x, const float* __restrict__ s,
    const short* __restrict__ wgt, const float* __restrict__ osc,
    float* __restrict__ out) {

    __shared__ __align__(16) short w_lds[9 * 8 * 64 * 8];    // 36864 sh = 73728 B
    __shared__ __align__(16) short x_lds[2][10 * 66 * CK];   // 2*42240 B

    const int tid = threadIdx.x;
    const int lane = tid & 63;
    const int wid = tid >> 6;          // 0..7 = output row within tile
    const int l15 = lane & 15;
    const int l4 = lane >> 4;

    // XCD-aware mapping: b == xcd (each XCD owns one batch sample's x slice);
    // the 4 ct-blocks of one (b,rt) group share that slice in L2.
    // bx = xcd + 8*ct + 32*ghi, bijective over 256.
    const int bx = blockIdx.x;
    const int xcd = bx & 7;
    const int t7 = bx >> 3;            // 0..31
    const int ct = t7 & 3;
    const int ghi = t7 >> 2;           // 0..7
    const int b = xcd;
    const int rt = ghi;                // 0..7
    const int r0 = rt * 8;

    // staging lane mapping: 4 cig x 64 col x 2 rowhalf
    const int cig = tid & 3;               // ci 8-block
    const int col = (tid >> 2) & 63;
    const int rowhalf = tid >> 8;          // 0/1

    // zero halo columns (lcol 0 and 65) of both buffers, once (uint writes)
    for (int i = tid; i < 640; i += 512) {
        int bufi = i >= 320;
        int v = i - bufi * 320;
        int row = v >> 5;
        int w16 = v & 31;
        int colh = (w16 >= 16) ? 65 : 0;
        int q16 = w16 & 15;
        ((unsigned*)x_lds[bufi])[(row * 66 + colh) * 16 + q16] = 0u;
    }

    float rx[40];
    float4v sva, svb;

    auto stage_w = [&](int c) {
        const short* src = wgt + (c * 4 + ct) * 36864;
#pragma unroll
        for (int k = 0; k < 9; ++k) {
            int off = (k * 512 + wid * 64) * 8;   // shorts, wave-uniform
            async_ld16(src + off + lane * 8, w_lds + off);
        }
    };

    auto stage_x_load = [&](int c) {
        const float4v* sp = (const float4v*)&s[b * CDIM + c * 32 + cig * 8];
        sva = sp[0]; svb = sp[1];
#pragma unroll
        for (int i = 0; i < 5; ++i) {
            int row = 2 * i + rowhalf;         // 0..9
            int grow = r0 - 1 + row;
            bool ok = (grow >= 0) && (grow < HW);
            const float* base = x + ((b * CDIM + c * 32 + cig * 8) * HW + (ok ? grow : 0)) * HW + col;
#pragma unroll
            for (int j = 0; j < 8; ++j) {
                float v = base[j * (HW * HW)];
                rx[i * 8 + j] = ok ? v : 0.0f;
            }
        }
    };

    auto stage_x_write = [&](int buf) {
        int lcol = col + 1;
        int q = cig ^ ((lcol >> 1) & 3);
#pragma unroll
        for (int i = 0; i < 5; ++i) {
            int row = 2 * i + rowhalf;
            short8 pk;
#pragma unroll
            for (int j = 0; j < 8; ++j) {
                float sj = (j < 4) ? sva[j] : svb[j - 4];
                pk[j] = f2bf(rx[i * 8 + j] * sj);
            }
            *(short8*)&x_lds[buf][(row * 66 + lcol) * CK + q * 8] = pk;
        }
    };

    float4v acc[8][4] = {};

    auto compute = [&](int buf) {
        const short* xb = x_lds[buf];
#pragma unroll
        for (int t = 0; t < 9; ++t) {
            int dh = t / 3 - 1;
            int dw = t % 3 - 1;
            int lrow = wid + dh + 1;   // 0..9
            short8 bfr[4];
#pragma unroll
            for (int nf = 0; nf < 4; ++nf) {
                int lcol = 1 + nf * 16 + l15 + dw;
                int xq = l4 ^ ((lcol >> 1) & 3);
                bfr[nf] = *(const short8*)&xb[(lrow * 66 + lcol) * CK + xq * 8];
            }
#pragma unroll
            for (int mf = 0; mf < 8; ++mf) {
                short8 af = *(const short8*)&w_lds[((t * 8 + mf) * 64 + lane) * 8];
#pragma unroll
                for (int nf = 0; nf < 4; ++nf)
                    acc[mf][nf] = __builtin_amdgcn_mfma_f32_16x16x32_bf16(
                        af, bfr[nf], acc[mf][nf], 0, 0, 0);
            }
        }
    };

    // prologue
    stage_w(0);
    stage_x_load(0);
    stage_x_write(0);
    hard_sync();

    int cur = 0;
#pragma unroll 1
    for (int c = 0; c < NCHUNK; ++c) {
        if (c + 1 < NCHUNK) stage_x_load(c + 1);   // issue early, hide under MFMA
        compute(cur);
        if (c + 1 < NCHUNK) {
            hard_sync();                            // all waves done with w_lds & x_lds[cur^1]
            stage_w(c + 1);                         // async global->LDS
            stage_x_write(cur ^ 1);                 // modulate + bf16 + ds_write
            hard_sync();                            // explicit vmcnt(0)+lgkm(0) drain, then barrier
            cur ^= 1;
        }
    }

    // epilogue: demodulate + store
    const int row_out = r0 + wid;
#pragma unroll
    for (int mf = 0; mf < 8; ++mf) {
        float4v ov = *(const float4v*)&osc[b * CDIM + ct * 128 + mf * 16 + l4 * 4];
#pragma unroll
        for (int j = 0; j < 4; ++j) {
            int co = ct * 128 + mf * 16 + l4 * 4 + j;
            float* po = out + ((b * CDIM + co) * HW + row_out) * HW;
#pragma unroll
            for (int nf = 0; nf < 4; ++nf)
                po[nf * 16 + l15] = acc[mf][nf][j] * ov[j];
        }
    }
}

// ---------------- launcher ----------------

extern "C" void kernel_launch(void* const* d_in, const int* in_sizes, int n_in,
                              void* d_out, int out_size, void* d_ws, size_t ws_size,
                              hipStream_t stream) {
    const float* x     = (const float*)d_in[0];   // 8*512*64*64
    const float* style = (const float*)d_in[1];   // 8*512
    const float* w     = (const float*)d_in[2];   // 512*512*9
    const float* aw    = (const float*)d_in[3];   // 512*512
    const float* ab    = (const float*)d_in[4];   // 512
    float* out = (float*)d_out;

    float* s_buf = (float*)d_ws;                 // 4096
    float* ws2   = s_buf + 4096;                 // 262144
    float* osc   = ws2 + 262144;                 // 4096
    short* wgt   = (short*)(osc + 4096);         // 2359296 shorts (~4.5 MB)

    k_affine<<<dim3(8, 2), 256, 0, stream>>>(style, aw, ab, s_buf);
    k_ws2<<<1024, 256, 0, stream>>>(w, ws2);
    k_wconv<<<9216, 256, 0, stream>>>(w, wgt);
    k_oscale<<<dim3(8, 2), 256, 0, stream>>>(s_buf, ws2, osc);
    conv_main<<<256, 512, 0, stream>>>(x, s_buf, wgt, osc, out);
}